// Round 1
// baseline (763.970 us; speedup 1.0000x reference)
//
#include <hip/hip_runtime.h>

constexpr int ATOM = 34;
constexpr int HID = 256;
constexpr int LATENT = 128;
constexpr int CELLS = 512;
constexpr int NN = 128;      // atoms per graph
constexpr int BLOCK = 512;   // 8 waves
constexpr int XP = ATOM + 2; // padded LDS row stride (36)

#define NEGF (-9e15f)

__global__ __launch_bounds__(BLOCK) void disease_fused(
    const float* __restrict__ xs, const int* __restrict__ A,
    const float* __restrict__ cell_emb,
    const float* __restrict__ Wg, const float* __restrict__ bg,
    const float* __restrict__ attnv,
    const float* __restrict__ Wt, const float* __restrict__ bt,
    const float* __restrict__ Wf, const float* __restrict__ bf,
    const float* __restrict__ Wf2, const float* __restrict__ bf2,
    const float* __restrict__ W1, const float* __restrict__ b1,
    const float* __restrict__ W2, const float* __restrict__ b2,
    const float* __restrict__ W3, const float* __restrict__ b3,
    const float* __restrict__ W4, const float* __restrict__ b4,
    float* __restrict__ out)
{
    const int b    = blockIdx.x;
    const int tid  = threadIdx.x;
    const int lane = tid & 63;
    const int wave = tid >> 6;   // 0..7

    __shared__ float x_lds[NN][XP];          // 18.4 KB  running node features
    __shared__ float h_lds[NN][XP];          // 18.4 KB  per-round h (reused as scratch)
    __shared__ float att_lds[NN * NN];       // 64   KB  attention matrix / generic scratch
    __shared__ unsigned long long mask_lds[NN][2]; // 2 KB adjacency bitmask
    __shared__ float fsrc[NN], fdst[NN];
    __shared__ float wg_lds[ATOM * ATOM];
    __shared__ float bg_lds[ATOM];
    __shared__ float a_lds[2 * ATOM];
    __shared__ float vec[LATENT + CELLS];
    __shared__ float h1s[128], h2s[256], h3s[512];

    const long xbase = (long)b * NN * ATOM;

    // ---- load xs into LDS (coalesced) ----
    for (int idx = tid; idx < NN * ATOM; idx += BLOCK) {
        int n = idx / ATOM, d = idx - n * ATOM;
        x_lds[n][d] = xs[xbase + idx];
    }
    // ---- build adjacency bitmask via ballot (reads A once) ----
    {
        const int* Ab = A + (long)b * NN * NN;
        for (int p = wave; p < NN; p += 8) {
            unsigned long long m0 = __ballot(Ab[p * NN + lane] > 0);
            unsigned long long m1 = __ballot(Ab[p * NN + 64 + lane] > 0);
            if (lane == 0) { mask_lds[p][0] = m0; mask_lds[p][1] = m1; }
        }
    }
    __syncthreads();

    // =================== 3 GAT rounds ===================
    for (int r = 0; r < 3; ++r) {
        for (int idx = tid; idx < ATOM * ATOM; idx += BLOCK)
            wg_lds[idx] = Wg[r * ATOM * ATOM + idx];
        if (tid < ATOM)      bg_lds[tid] = bg[r * ATOM + tid];
        if (tid < 2 * ATOM)  a_lds[tid]  = attnv[r * 2 * ATOM + tid];
        __syncthreads();

        // h = relu(x @ Wg + bg)
        for (int idx = tid; idx < NN * ATOM; idx += BLOCK) {
            int n = idx / ATOM, e = idx - n * ATOM;
            float acc = bg_lds[e];
            #pragma unroll 2
            for (int d = 0; d < ATOM; ++d)
                acc += x_lds[n][d] * wg_lds[d * ATOM + e];
            h_lds[n][e] = fmaxf(acc, 0.f);
        }
        __syncthreads();

        // f_src / f_dst (34-dots per row)
        if (tid < 2 * NN) {
            int n = tid & (NN - 1);
            const float* av = (tid < NN) ? a_lds : (a_lds + ATOM);
            float acc = 0.f;
            #pragma unroll 2
            for (int d = 0; d < ATOM; ++d) acc += h_lds[n][d] * av[d];
            if (tid < NN) fsrc[n] = acc; else fdst[n] = acc;
        }
        __syncthreads();

        // masked softmax per row -> att_lds (one wave per row, 2 cols/lane)
        for (int p = wave; p < NN; p += 8) {
            float fs = fsrc[p];
            unsigned long long m0 = mask_lds[p][0], m1 = mask_lds[p][1];
            float s0 = fs + fdst[lane];
            s0 = (s0 > 0.f) ? s0 : 0.01f * s0;           // leaky_relu BEFORE mask
            if (!((m0 >> lane) & 1ull)) s0 = NEGF;
            float s1 = fs + fdst[64 + lane];
            s1 = (s1 > 0.f) ? s1 : 0.01f * s1;
            if (!((m1 >> lane) & 1ull)) s1 = NEGF;
            float mx = fmaxf(s0, s1);
            #pragma unroll
            for (int o = 32; o >= 1; o >>= 1) mx = fmaxf(mx, __shfl_xor(mx, o, 64));
            float e0 = __expf(s0 - mx), e1 = __expf(s1 - mx);
            float sm = e0 + e1;
            #pragma unroll
            for (int o = 32; o >= 1; o >>= 1) sm += __shfl_xor(sm, o, 64);
            float inv = 1.f / sm;
            att_lds[p * NN + lane]      = e0 * inv;
            att_lds[p * NN + 64 + lane] = e1 * inv;
        }
        __syncthreads();

        // x += att @ h   (each (p,d) owned by exactly one thread)
        for (int idx = tid; idx < NN * ATOM; idx += BLOCK) {
            int p = idx / ATOM, d = idx - p * ATOM;
            float acc = x_lds[p][d];
            #pragma unroll 4
            for (int q = 0; q < NN; ++q)
                acc += att_lds[p * NN + q] * h_lds[q][d];
            x_lds[p][d] = acc;
        }
        __syncthreads();
    }

    // =================== Phase B: g=relu(x@Wt+bt); d=g@Wf+bf+xs (fused, g never materialized) ===================
    {
        const int rr  = tid & (NN - 1);
        const int sub = tid >> 7;            // 0..3, 64 hidden dims each
        float xr[ATOM];
        #pragma unroll
        for (int d = 0; d < ATOM; ++d) xr[d] = x_lds[rr][d];   // register-cache row
        float dpart[ATOM];
        #pragma unroll
        for (int j = 0; j < ATOM; ++j) dpart[j] = 0.f;
        for (int i = 0; i < HID / 4; ++i) {
            const int hh = sub * (HID / 4) + i;                // wave-uniform -> scalar loads
            float acc = bt[hh];
            #pragma unroll 2
            for (int d = 0; d < ATOM; ++d) acc += xr[d] * Wt[d * HID + hh];
            float gv = fmaxf(acc, 0.f);
            #pragma unroll 2
            for (int j = 0; j < ATOM; ++j) dpart[j] += gv * Wf[hh * ATOM + j];
        }
        // partials: sub 0..2 -> att_lds[rr*128 + sub*34 + j], sub 3 -> h_lds[rr][j]
        if (sub < 3) {
            #pragma unroll
            for (int j = 0; j < ATOM; ++j) att_lds[rr * NN + sub * ATOM + j] = dpart[j];
        } else {
            #pragma unroll
            for (int j = 0; j < ATOM; ++j) h_lds[rr][j] = dpart[j];
        }
        __syncthreads();
        if (tid < NN) {
            #pragma unroll 2
            for (int j = 0; j < ATOM; ++j) {
                float dv = att_lds[tid * NN + j] + att_lds[tid * NN + ATOM + j]
                         + att_lds[tid * NN + 2 * ATOM + j] + h_lds[tid][j]
                         + bf[j] + xs[xbase + tid * ATOM + j];
                x_lds[tid][j] = dv;          // x now holds d [128][34]
            }
        }
        __syncthreads();
    }

    // =================== d2 = d@Wf2+bf2 ; column max over rows ; sigmoid-concat ===================
    {
        const int l     = tid & 127;
        const int chunk = tid >> 7;          // 4 chunks x 32 rows
        float mx = -3.4e38f;
        for (int rr = chunk * 32; rr < chunk * 32 + 32; ++rr) {
            float acc = bf2[l];
            #pragma unroll 2
            for (int j = 0; j < ATOM; ++j)
                acc += x_lds[rr][j] * Wf2[j * LATENT + l];   // Wf2 coalesced across lanes
            mx = fmaxf(mx, acc);
        }
        att_lds[chunk * 128 + l] = mx;
        __syncthreads();
        if (tid < LATENT) {
            float m = fmaxf(fmaxf(att_lds[tid], att_lds[128 + tid]),
                            fmaxf(att_lds[256 + tid], att_lds[384 + tid]));
            vec[tid] = 1.f / (1.f + __expf(-m));
        }
        vec[LATENT + tid] = 1.f / (1.f + __expf(-cell_emb[(long)b * CELLS + tid]));
        __syncthreads();
    }

    // =================== Decoder MLP ===================
    {
        // h1: 128 outputs, K=640 split 4 ways
        const int j = tid & 127, part = tid >> 7;
        float acc = 0.f;
        for (int k = part * 160; k < part * 160 + 160; ++k)
            acc += vec[k] * W1[k * 128 + j];                 // coalesced across lanes
        att_lds[part * 128 + j] = acc;
        __syncthreads();
        if (tid < 128) {
            float v = att_lds[tid] + att_lds[128 + tid] + att_lds[256 + tid]
                    + att_lds[384 + tid] + b1[tid];
            h1s[tid] = fmaxf(v, 0.f);
        }
        __syncthreads();
        if (tid < 256) {
            float acc2 = b2[tid];
            #pragma unroll 4
            for (int k = 0; k < 128; ++k) acc2 += h1s[k] * W2[k * 256 + tid];
            h2s[tid] = fmaxf(acc2, 0.f);
        }
        __syncthreads();
        {
            float acc3 = b3[tid];
            #pragma unroll 4
            for (int k = 0; k < 256; ++k) acc3 += h2s[k] * W3[k * 512 + tid];
            h3s[tid] = fmaxf(acc3, 0.f);
        }
        __syncthreads();
        // score = h3 . W4 + b4  (block reduce)
        float v = h3s[tid] * W4[tid];
        #pragma unroll
        for (int o = 32; o >= 1; o >>= 1) v += __shfl_xor(v, o, 64);
        if (lane == 0) att_lds[wave] = v;
        __syncthreads();
        if (tid == 0) {
            float s = b4[0];
            #pragma unroll
            for (int w = 0; w < 8; ++w) s += att_lds[w];
            out[b] = s;
        }
    }
}

extern "C" void kernel_launch(void* const* d_in, const int* in_sizes, int n_in,
                              void* d_out, int out_size, void* d_ws, size_t ws_size,
                              hipStream_t stream) {
    const float* xs       = (const float*)d_in[0];
    const int*   A        = (const int*)  d_in[1];
    const float* cell_emb = (const float*)d_in[2];
    const float* Wg       = (const float*)d_in[3];
    const float* bg       = (const float*)d_in[4];
    const float* attnv    = (const float*)d_in[5];
    const float* Wt       = (const float*)d_in[6];
    const float* bt       = (const float*)d_in[7];
    const float* Wf       = (const float*)d_in[8];
    const float* bf       = (const float*)d_in[9];
    const float* Wf2      = (const float*)d_in[10];
    const float* bf2      = (const float*)d_in[11];
    const float* W1       = (const float*)d_in[12];
    const float* b1       = (const float*)d_in[13];
    const float* W2       = (const float*)d_in[14];
    const float* b2       = (const float*)d_in[15];
    const float* W3       = (const float*)d_in[16];
    const float* b3       = (const float*)d_in[17];
    const float* W4       = (const float*)d_in[18];
    const float* b4       = (const float*)d_in[19];
    float* out = (float*)d_out;

    disease_fused<<<64, BLOCK, 0, stream>>>(
        xs, A, cell_emb, Wg, bg, attnv, Wt, bt, Wf, bf, Wf2, bf2,
        W1, b1, W2, b2, W3, b3, W4, b4, out);
}

// Round 2
// 215.003 us; speedup vs baseline: 3.5533x; 3.5533x over previous
//
#include <hip/hip_runtime.h>

constexpr int ATOM = 34;
constexpr int HID = 256;
constexpr int LATENT = 128;
constexpr int CELLS = 512;
constexpr int NN = 128;
constexpr int NA = NN * ATOM;   // 4352
#define NEGF (-9e15f)

// ---------------- K1: h = relu(x@Wg+bg); fsrc/fdst ----------------
// grid 256 = 64 batches x 4 row-quarters, block 256
__global__ __launch_bounds__(256) void k_gat_h(
    const float* __restrict__ xsrc, const float* __restrict__ Wg,
    const float* __restrict__ bg, const float* __restrict__ av,
    float* __restrict__ H, float* __restrict__ FS, float* __restrict__ FD)
{
    const int b = blockIdx.x >> 2, qq = blockIdx.x & 3;
    const int t = threadIdx.x;
    const int p0 = qq * 32;
    __shared__ float wg[ATOM * ATOM];
    __shared__ float xl[32][ATOM + 1];
    __shared__ float hl[32][ATOM + 1];
    __shared__ float bgs[ATOM], avs[2 * ATOM];
    for (int i = t; i < ATOM * ATOM; i += 256) wg[i] = Wg[i];
    if (t < ATOM)     bgs[t] = bg[t];
    if (t < 2 * ATOM) avs[t] = av[t];
    const float* xp = xsrc + b * NA + p0 * ATOM;
    for (int i = t; i < 32 * ATOM; i += 256) xl[i / ATOM][i % ATOM] = xp[i];
    __syncthreads();
    float* hp = H + b * NA + p0 * ATOM;
    for (int i = t; i < 32 * ATOM; i += 256) {
        int n = i / ATOM, e = i % ATOM;
        float acc = bgs[e];
        #pragma unroll
        for (int d = 0; d < ATOM; ++d) acc += xl[n][d] * wg[d * ATOM + e];
        acc = fmaxf(acc, 0.f);
        hl[n][e] = acc;
        hp[i] = acc;
    }
    __syncthreads();
    if (t < 64) {
        int n = t & 31, w = t >> 5;
        float acc = 0.f;
        #pragma unroll
        for (int d = 0; d < ATOM; ++d) acc += hl[n][d] * avs[w * ATOM + d];
        if (w == 0) FS[b * NN + p0 + n] = acc;
        else        FD[b * NN + p0 + n] = acc;
    }
}

// ---------------- K2: masked softmax + x += att@h ----------------
// grid 256, block 256 (4 waves x 8 rows each)
__global__ __launch_bounds__(256) void k_gat_agg(
    const float* __restrict__ xsrc, const int* __restrict__ A,
    const float* __restrict__ H, const float* __restrict__ FS,
    const float* __restrict__ FD, float* __restrict__ X)
{
    const int b = blockIdx.x >> 2, qq = blockIdx.x & 3;
    const int t = threadIdx.x, lane = t & 63, wave = t >> 6;
    const int p0 = qq * 32;
    __shared__ float hl[NN][ATOM + 1];
    __shared__ float att[32][NN];
    __shared__ float fd[NN];
    __shared__ float fs[32];
    for (int i = t; i < NA; i += 256) hl[i / ATOM][i % ATOM] = H[b * NA + i];
    if (t < NN) fd[t] = FD[b * NN + t];
    if (t < 32) fs[t] = FS[b * NN + p0 + t];
    __syncthreads();
    const int* Ab = A + b * NN * NN;
    for (int i = 0; i < 8; ++i) {
        int p = wave * 8 + i;
        float fsv = fs[p];
        unsigned long long m0 = __ballot(Ab[(p0 + p) * NN + lane] > 0);
        unsigned long long m1 = __ballot(Ab[(p0 + p) * NN + 64 + lane] > 0);
        float s0 = fsv + fd[lane];
        s0 = (s0 > 0.f) ? s0 : 0.01f * s0;
        if (!((m0 >> lane) & 1ull)) s0 = NEGF;
        float s1 = fsv + fd[64 + lane];
        s1 = (s1 > 0.f) ? s1 : 0.01f * s1;
        if (!((m1 >> lane) & 1ull)) s1 = NEGF;
        float mx = fmaxf(s0, s1);
        #pragma unroll
        for (int o = 32; o >= 1; o >>= 1) mx = fmaxf(mx, __shfl_xor(mx, o, 64));
        float e0 = __expf(s0 - mx), e1 = __expf(s1 - mx);
        float sm = e0 + e1;
        #pragma unroll
        for (int o = 32; o >= 1; o >>= 1) sm += __shfl_xor(sm, o, 64);
        float inv = 1.f / sm;
        att[p][lane] = e0 * inv;
        att[p][64 + lane] = e1 * inv;
    }
    __syncthreads();
    for (int i = t; i < 32 * ATOM; i += 256) {
        int p = i / ATOM, d = i % ATOM;
        float acc = xsrc[b * NA + (p0 + p) * ATOM + d];
        #pragma unroll 4
        for (int q = 0; q < NN; ++q) acc += att[p][q] * hl[q][d];
        X[b * NA + (p0 + p) * ATOM + d] = acc;
    }
}

// ---------------- K3: g=relu(x@Wt+bt); d=g@Wf+bf+xs; d@Wf2+bf2; partial col-max ----------------
// grid 256, block 256 = 32 rows x 8 h-subgroups
__global__ __launch_bounds__(256) void k_phaseB(
    const float* __restrict__ X, const float* __restrict__ xs,
    const float* __restrict__ Wt, const float* __restrict__ bt,
    const float* __restrict__ Wf, const float* __restrict__ bf,
    const float* __restrict__ Wf2, const float* __restrict__ bf2,
    float* __restrict__ DM)
{
    const int b = blockIdx.x >> 2, qq = blockIdx.x & 3;
    const int t = threadIdx.x;
    const int p0 = qq * 32;
    __shared__ float wt[HID * (ATOM + 1)];   // [h][d], pad 35 (reused as partial store)
    __shared__ float wf[HID * (ATOM + 1)];   // [h][j]
    __shared__ float bts[HID];
    __shared__ float bfs[ATOM];
    __shared__ float xl[32][ATOM + 1];
    __shared__ float dl[32][ATOM + 1];
    __shared__ float sl[256];

    for (int i = t; i < ATOM * HID; i += 256) { int d = i / HID, h = i % HID; wt[h * 35 + d] = Wt[i]; }
    for (int i = t; i < HID * ATOM; i += 256) { int h = i / ATOM, j = i % ATOM; wf[h * 35 + j] = Wf[i]; }
    bts[t] = bt[t];
    if (t < ATOM) bfs[t] = bf[t];
    for (int i = t; i < 32 * ATOM; i += 256) xl[i / ATOM][i % ATOM] = X[b * NA + p0 * ATOM + i];
    __syncthreads();

    const int row = t & 31, sub = t >> 5;    // h = sub + 8*i keeps LDS banks spread
    float xr[ATOM];
    #pragma unroll
    for (int d = 0; d < ATOM; ++d) xr[d] = xl[row][d];
    float dp[ATOM];
    #pragma unroll
    for (int j = 0; j < ATOM; ++j) dp[j] = 0.f;
    for (int i = 0; i < 32; ++i) {
        const int h = sub + 8 * i;
        float acc = bts[h];
        #pragma unroll
        for (int d = 0; d < ATOM; ++d) acc += xr[d] * wt[h * 35 + d];
        acc = fmaxf(acc, 0.f);
        #pragma unroll
        for (int j = 0; j < ATOM; ++j) dp[j] += acc * wf[h * 35 + j];
    }
    __syncthreads();                          // done reading wt -> reuse as partial buffer
    float* pl = wt;                           // [sub][row][j] : 8*32*34 = 8704 <= 8960
    #pragma unroll
    for (int j = 0; j < ATOM; ++j) pl[(sub * 32 + row) * ATOM + j] = dp[j];
    __syncthreads();
    for (int i = t; i < 32 * ATOM; i += 256) {
        int rr = i / ATOM, j = i % ATOM;
        float dv = bfs[j] + xs[b * NA + (p0 + rr) * ATOM + j];
        #pragma unroll
        for (int s = 0; s < 8; ++s) dv += pl[(s * 32 + rr) * ATOM + j];
        dl[rr][j] = dv;
    }
    __syncthreads();
    // d @ Wf2 + bf2, partial max over this block's 32 rows
    const int l = t & 127, half = t >> 7;
    float mx = -3.4e38f;
    for (int rr = half * 16; rr < half * 16 + 16; ++rr) {
        float acc = bf2[l];
        #pragma unroll
        for (int j = 0; j < ATOM; ++j) acc += dl[rr][j] * Wf2[j * LATENT + l];
        mx = fmaxf(mx, acc);
    }
    sl[half * 128 + l] = mx;
    __syncthreads();
    if (t < LATENT) DM[(b * 4 + qq) * LATENT + t] = fmaxf(sl[t], sl[128 + t]);
}

// ---------------- K4: vec assembly + decoder MLP ----------------
// grid 64, block 512
__global__ __launch_bounds__(512) void k_decoder(
    const float* __restrict__ DM, const float* __restrict__ cell,
    const float* __restrict__ W1, const float* __restrict__ b1,
    const float* __restrict__ W2, const float* __restrict__ b2,
    const float* __restrict__ W3, const float* __restrict__ b3,
    const float* __restrict__ W4, const float* __restrict__ b4,
    float* __restrict__ out)
{
    const int b = blockIdx.x, t = threadIdx.x, lane = t & 63, wave = t >> 6;
    __shared__ float vec[LATENT + CELLS];
    __shared__ float h1[128], h2[256], h3[512], sl[512];
    if (t < LATENT) {
        float m = fmaxf(fmaxf(DM[(b * 4 + 0) * LATENT + t], DM[(b * 4 + 1) * LATENT + t]),
                        fmaxf(DM[(b * 4 + 2) * LATENT + t], DM[(b * 4 + 3) * LATENT + t]));
        vec[t] = 1.f / (1.f + __expf(-m));
    }
    vec[LATENT + t] = 1.f / (1.f + __expf(-cell[b * CELLS + t]));
    __syncthreads();
    {
        const int j = t & 127, part = t >> 7;
        float acc = 0.f;
        for (int k = part * 160; k < part * 160 + 160; ++k)
            acc += vec[k] * W1[k * 128 + j];
        sl[part * 128 + j] = acc;
    }
    __syncthreads();
    if (t < 128)
        h1[t] = fmaxf(sl[t] + sl[128 + t] + sl[256 + t] + sl[384 + t] + b1[t], 0.f);
    __syncthreads();
    if (t < 256) {
        float a = b2[t];
        #pragma unroll 4
        for (int k = 0; k < 128; ++k) a += h1[k] * W2[k * 256 + t];
        h2[t] = fmaxf(a, 0.f);
    }
    __syncthreads();
    {
        float a = b3[t];
        #pragma unroll 4
        for (int k = 0; k < 256; ++k) a += h2[k] * W3[k * 512 + t];
        h3[t] = fmaxf(a, 0.f);
    }
    __syncthreads();
    float v = h3[t] * W4[t];
    #pragma unroll
    for (int o = 32; o >= 1; o >>= 1) v += __shfl_xor(v, o, 64);
    if (lane == 0) sl[wave] = v;
    __syncthreads();
    if (t == 0) {
        float s = b4[0];
        #pragma unroll
        for (int w = 0; w < 8; ++w) s += sl[w];
        out[b] = s;
    }
}

extern "C" void kernel_launch(void* const* d_in, const int* in_sizes, int n_in,
                              void* d_out, int out_size, void* d_ws, size_t ws_size,
                              hipStream_t stream) {
    const float* xs       = (const float*)d_in[0];
    const int*   A        = (const int*)  d_in[1];
    const float* cell_emb = (const float*)d_in[2];
    const float* Wg       = (const float*)d_in[3];
    const float* bg       = (const float*)d_in[4];
    const float* attnv    = (const float*)d_in[5];
    const float* Wt       = (const float*)d_in[6];
    const float* bt       = (const float*)d_in[7];
    const float* Wf       = (const float*)d_in[8];
    const float* bf       = (const float*)d_in[9];
    const float* Wf2      = (const float*)d_in[10];
    const float* bf2      = (const float*)d_in[11];
    const float* W1       = (const float*)d_in[12];
    const float* b1       = (const float*)d_in[13];
    const float* W2       = (const float*)d_in[14];
    const float* b2       = (const float*)d_in[15];
    const float* W3       = (const float*)d_in[16];
    const float* b3       = (const float*)d_in[17];
    const float* W4       = (const float*)d_in[18];
    const float* b4       = (const float*)d_in[19];
    float* out = (float*)d_out;

    float* W  = (float*)d_ws;
    float* H  = W;
    float* Xb = W + 278528;
    float* FS = W + 557056;
    float* FD = W + 565248;
    float* DM = W + 573440;   // total 606208 floats = 2.42 MB

    for (int r = 0; r < 3; ++r) {
        const float* xsrc = (r == 0) ? xs : Xb;
        k_gat_h  <<<256, 256, 0, stream>>>(xsrc, Wg + r * ATOM * ATOM, bg + r * ATOM,
                                           attnv + r * 2 * ATOM, H, FS, FD);
        k_gat_agg<<<256, 256, 0, stream>>>(xsrc, A, H, FS, FD, Xb);
    }
    k_phaseB <<<256, 256, 0, stream>>>(Xb, xs, Wt, bt, Wf, bf, Wf2, bf2, DM);
    k_decoder<<<64, 512, 0, stream>>>(DM, cell_emb, W1, b1, W2, b2, W3, b3, W4, b4, out);
}

// Round 3
// 209.230 us; speedup vs baseline: 3.6513x; 1.0276x over previous
//
#include <hip/hip_runtime.h>

constexpr int ATOM = 34;
constexpr int HID = 256;
constexpr int LATENT = 128;
constexpr int CELLS = 512;
constexpr int NN = 128;
constexpr int NA = NN * ATOM;   // 4352
#define NEGF (-9e15f)

// ---------------- K1: fused GAT round ----------------
// grid 256 = 64 batches x 4 row-quarters, block 512
// Each block recomputes h for ALL 128 rows (cheap), then softmax+aggregate
// for its own 32 rows.
__global__ __launch_bounds__(512) void k_gat(
    const float* __restrict__ xsrc, const int* __restrict__ A,
    const float* __restrict__ Wg, const float* __restrict__ bg,
    const float* __restrict__ av, float* __restrict__ X)
{
    const int b = blockIdx.x >> 2, qq = blockIdx.x & 3;
    const int t = threadIdx.x, lane = t & 63, wave = t >> 6;
    const int p0 = qq * 32;

    __shared__ float xl[NN][ATOM + 1];   // 17.9 KB (input x, full batch)
    __shared__ float hl[NN][ATOM + 1];   // 17.9 KB
    __shared__ float att[32][NN];        // 16 KB
    __shared__ float fs[NN], fd[NN];
    __shared__ float wg[ATOM * ATOM];
    __shared__ float bgs[ATOM], avs[2 * ATOM];

    for (int i = t; i < ATOM * ATOM; i += 512) wg[i] = Wg[i];
    if (t < ATOM)     bgs[t] = bg[t];
    if (t < 2 * ATOM) avs[t] = av[t];
    const float* xp = xsrc + b * NA;
    for (int i = t; i < NA; i += 512) xl[i / ATOM][i % ATOM] = xp[i];
    __syncthreads();

    // h = relu(x @ Wg + bg), all 128 rows
    for (int i = t; i < NA; i += 512) {
        int n = i / ATOM, e = i % ATOM;
        float acc = bgs[e];
        #pragma unroll
        for (int d = 0; d < ATOM; ++d) acc += xl[n][d] * wg[d * ATOM + e];
        hl[n][e] = fmaxf(acc, 0.f);
    }
    __syncthreads();

    // fs/fd for all rows
    if (t < 2 * NN) {
        int n = t & (NN - 1), w = t >> 7;
        float acc = 0.f;
        #pragma unroll
        for (int d = 0; d < ATOM; ++d) acc += hl[n][d] * avs[w * ATOM + d];
        if (w == 0) fs[n] = acc; else fd[n] = acc;
    }
    __syncthreads();

    // masked softmax for this block's 32 rows (8 waves x 4 rows)
    const int* Ab = A + b * NN * NN;
    #pragma unroll
    for (int i = 0; i < 4; ++i) {
        int lp = wave * 4 + i, gp = p0 + lp;
        float fsv = fs[gp];
        unsigned long long m0 = __ballot(Ab[gp * NN + lane] > 0);
        unsigned long long m1 = __ballot(Ab[gp * NN + 64 + lane] > 0);
        float s0 = fsv + fd[lane];
        s0 = (s0 > 0.f) ? s0 : 0.01f * s0;
        if (!((m0 >> lane) & 1ull)) s0 = NEGF;
        float s1 = fsv + fd[64 + lane];
        s1 = (s1 > 0.f) ? s1 : 0.01f * s1;
        if (!((m1 >> lane) & 1ull)) s1 = NEGF;
        float mx = fmaxf(s0, s1);
        #pragma unroll
        for (int o = 32; o >= 1; o >>= 1) mx = fmaxf(mx, __shfl_xor(mx, o, 64));
        float e0 = __expf(s0 - mx), e1 = __expf(s1 - mx);
        float sm = e0 + e1;
        #pragma unroll
        for (int o = 32; o >= 1; o >>= 1) sm += __shfl_xor(sm, o, 64);
        float inv = 1.f / sm;
        att[lp][lane]      = e0 * inv;
        att[lp][64 + lane] = e1 * inv;
    }
    __syncthreads();

    // x_out = x + att @ h for this block's rows
    for (int i = t; i < 32 * ATOM; i += 512) {
        int lp = i / ATOM, d = i % ATOM, gp = p0 + lp;
        float acc = xl[gp][d];
        #pragma unroll 4
        for (int q = 0; q < NN; ++q) acc += att[lp][q] * hl[q][d];
        X[b * NA + gp * ATOM + d] = acc;
    }
}

// ---------------- K2: phaseB ----------------
// grid 256, block 512 = 32 rows x 16 h-subgroups
__global__ __launch_bounds__(512) void k_phaseB(
    const float* __restrict__ X, const float* __restrict__ xs,
    const float* __restrict__ Wt, const float* __restrict__ bt,
    const float* __restrict__ Wf, const float* __restrict__ bf,
    const float* __restrict__ Wf2, const float* __restrict__ bf2,
    float* __restrict__ DM)
{
    const int b = blockIdx.x >> 2, qq = blockIdx.x & 3;
    const int t = threadIdx.x;
    const int p0 = qq * 32;
    __shared__ float wt[HID * (ATOM + 1)];   // [h][d] transposed; reused for partials 0..7
    __shared__ float wf[HID * (ATOM + 1)];   // [h][j]; reused for partials 8..15
    __shared__ float bts[HID];
    __shared__ float bfs[ATOM];
    __shared__ float xl[32][ATOM + 1];
    __shared__ float dl[32][ATOM + 1];
    __shared__ float sl[512];

    for (int i = t; i < ATOM * HID; i += 512) { int d = i / HID, h = i % HID; wt[h * 35 + d] = Wt[i]; }
    for (int i = t; i < HID * ATOM; i += 512) { int h = i / ATOM, j = i % ATOM; wf[h * 35 + j] = Wf[i]; }
    if (t < HID) bts[t] = bt[t];
    if (t < ATOM) bfs[t] = bf[t];
    for (int i = t; i < 32 * ATOM; i += 512) xl[i / ATOM][i % ATOM] = X[b * NA + p0 * ATOM + i];
    __syncthreads();

    const int row = t & 31, sub = t >> 5;    // sub 0..15
    float xr[ATOM];
    #pragma unroll
    for (int d = 0; d < ATOM; ++d) xr[d] = xl[row][d];
    float dp[ATOM];
    #pragma unroll
    for (int j = 0; j < ATOM; ++j) dp[j] = 0.f;
    #pragma unroll 2
    for (int i = 0; i < 16; ++i) {
        const int h = sub + 16 * i;
        float acc = bts[h];
        #pragma unroll
        for (int d = 0; d < ATOM; ++d) acc += xr[d] * wt[h * 35 + d];
        acc = fmaxf(acc, 0.f);
        #pragma unroll
        for (int j = 0; j < ATOM; ++j) dp[j] += acc * wf[h * 35 + j];
    }
    __syncthreads();                          // done reading wt/wf -> reuse as partial buffers
    float* pl = (sub < 8) ? wt : wf;          // 8*32*34 = 8704 floats each <= 8960
    #pragma unroll
    for (int j = 0; j < ATOM; ++j) pl[((sub & 7) * 32 + row) * ATOM + j] = dp[j];
    __syncthreads();
    for (int i = t; i < 32 * ATOM; i += 512) {
        int rr = i / ATOM, j = i % ATOM;
        float dv = bfs[j] + xs[b * NA + (p0 + rr) * ATOM + j];
        #pragma unroll
        for (int s = 0; s < 8; ++s)
            dv += wt[(s * 32 + rr) * ATOM + j] + wf[(s * 32 + rr) * ATOM + j];
        dl[rr][j] = dv;
    }
    __syncthreads();
    // d @ Wf2 + bf2, partial max over this block's 32 rows (4 chunks x 8 rows)
    const int l = t & 127, chunk = t >> 7;
    float mx = -3.4e38f;
    for (int rr = chunk * 8; rr < chunk * 8 + 8; ++rr) {
        float acc = bf2[l];
        #pragma unroll
        for (int j = 0; j < ATOM; ++j) acc += dl[rr][j] * Wf2[j * LATENT + l];
        mx = fmaxf(mx, acc);
    }
    sl[chunk * 128 + l] = mx;
    __syncthreads();
    if (t < LATENT)
        DM[(b * 4 + qq) * LATENT + t] =
            fmaxf(fmaxf(sl[t], sl[128 + t]), fmaxf(sl[256 + t], sl[384 + t]));
}

// ---------------- K3: vec assembly + layer1 ----------------
// grid 64, block 256
__global__ __launch_bounds__(256) void k_dec1(
    const float* __restrict__ DM, const float* __restrict__ cell,
    const float* __restrict__ W1, const float* __restrict__ b1,
    float* __restrict__ H1)
{
    const int b = blockIdx.x, t = threadIdx.x;
    __shared__ float vec[LATENT + CELLS];
    __shared__ float sl[256];
    if (t < LATENT) {
        float m = fmaxf(fmaxf(DM[(b * 4 + 0) * LATENT + t], DM[(b * 4 + 1) * LATENT + t]),
                        fmaxf(DM[(b * 4 + 2) * LATENT + t], DM[(b * 4 + 3) * LATENT + t]));
        vec[t] = 1.f / (1.f + __expf(-m));
    }
    vec[LATENT + t]       = 1.f / (1.f + __expf(-cell[b * CELLS + t]));
    vec[LATENT + 256 + t] = 1.f / (1.f + __expf(-cell[b * CELLS + 256 + t]));
    __syncthreads();
    const int j = t & 127, half = t >> 7;
    float acc = 0.f;
    for (int k = half * 320; k < half * 320 + 320; ++k)
        acc += vec[k] * W1[k * 128 + j];
    sl[half * 128 + j] = acc;
    __syncthreads();
    if (t < 128)
        H1[b * 128 + t] = fmaxf(sl[t] + sl[128 + t] + b1[t], 0.f);
}

// ---------------- K4: layers 2-4 ----------------
// grid 64, block 512
__global__ __launch_bounds__(512) void k_dec2(
    const float* __restrict__ H1,
    const float* __restrict__ W2, const float* __restrict__ b2,
    const float* __restrict__ W3, const float* __restrict__ b3,
    const float* __restrict__ W4, const float* __restrict__ b4,
    float* __restrict__ out)
{
    const int b = blockIdx.x, t = threadIdx.x, lane = t & 63, wave = t >> 6;
    __shared__ float h1[128], h2[256], h3[512], sl[512];
    if (t < 128) h1[t] = H1[b * 128 + t];
    __syncthreads();
    {
        const int j = t & 255, half = t >> 8;
        float acc = 0.f;
        #pragma unroll 4
        for (int k = half * 64; k < half * 64 + 64; ++k)
            acc += h1[k] * W2[k * 256 + j];
        sl[half * 256 + j] = acc;
    }
    __syncthreads();
    if (t < 256) h2[t] = fmaxf(sl[t] + sl[256 + t] + b2[t], 0.f);
    __syncthreads();
    {
        float acc = b3[t];
        #pragma unroll 4
        for (int k = 0; k < 256; ++k) acc += h2[k] * W3[k * 512 + t];
        h3[t] = fmaxf(acc, 0.f);
    }
    __syncthreads();
    float v = h3[t] * W4[t];
    #pragma unroll
    for (int o = 32; o >= 1; o >>= 1) v += __shfl_xor(v, o, 64);
    if (lane == 0) sl[wave] = v;
    __syncthreads();
    if (t == 0) {
        float s = b4[0];
        #pragma unroll
        for (int w = 0; w < 8; ++w) s += sl[w];
        out[b] = s;
    }
}

extern "C" void kernel_launch(void* const* d_in, const int* in_sizes, int n_in,
                              void* d_out, int out_size, void* d_ws, size_t ws_size,
                              hipStream_t stream) {
    const float* xs       = (const float*)d_in[0];
    const int*   A        = (const int*)  d_in[1];
    const float* cell_emb = (const float*)d_in[2];
    const float* Wg       = (const float*)d_in[3];
    const float* bg       = (const float*)d_in[4];
    const float* attnv    = (const float*)d_in[5];
    const float* Wt       = (const float*)d_in[6];
    const float* bt       = (const float*)d_in[7];
    const float* Wf       = (const float*)d_in[8];
    const float* bf       = (const float*)d_in[9];
    const float* Wf2      = (const float*)d_in[10];
    const float* bf2      = (const float*)d_in[11];
    const float* W1       = (const float*)d_in[12];
    const float* b1       = (const float*)d_in[13];
    const float* W2       = (const float*)d_in[14];
    const float* b2       = (const float*)d_in[15];
    const float* W3       = (const float*)d_in[16];
    const float* b3       = (const float*)d_in[17];
    const float* W4       = (const float*)d_in[18];
    const float* b4       = (const float*)d_in[19];
    float* out = (float*)d_out;

    float* W  = (float*)d_ws;
    float* Xb = W;                 // 64*4352
    float* DM = W + 278528;        // 64*4*128
    float* H1 = W + 311296;        // 64*128

    for (int r = 0; r < 3; ++r) {
        const float* xsrc = (r == 0) ? xs : Xb;
        k_gat<<<256, 512, 0, stream>>>(xsrc, A, Wg + r * ATOM * ATOM, bg + r * ATOM,
                                       attnv + r * 2 * ATOM, Xb);
    }
    k_phaseB<<<256, 512, 0, stream>>>(Xb, xs, Wt, bt, Wf, bf, Wf2, bf2, DM);
    k_dec1<<<64, 256, 0, stream>>>(DM, cell_emb, W1, b1, H1);
    k_dec2<<<64, 512, 0, stream>>>(H1, W2, b2, W3, b3, W4, b4, out);
}

// Round 4
// 178.612 us; speedup vs baseline: 4.2773x; 1.1714x over previous
//
#include <hip/hip_runtime.h>

constexpr int ATOM = 34;
constexpr int HID = 256;
constexpr int LATENT = 128;
constexpr int CELLS = 512;
constexpr int NN = 128;
constexpr int NA = NN * ATOM;   // 4352
#define NEGF (-9e15f)

// ---------------- K1: fused GAT round ----------------
// grid 256 = 64 batches x 4 row-quarters, block 512.
// h stored TRANSPOSED (hlT[d][q], stride 132 = 528B, 16B-aligned) so the
// att@h inner loop is pure ds_read_b128 on both operands.
__global__ __launch_bounds__(512) void k_gat(
    const float* __restrict__ xsrc, const int* __restrict__ A,
    const float* __restrict__ Wg, const float* __restrict__ bg,
    const float* __restrict__ av, float* __restrict__ X)
{
    const int b = blockIdx.x >> 2, q4 = blockIdx.x & 3;
    const int t = threadIdx.x, lane = t & 63, wave = t >> 6;
    const int p0 = q4 * 32;

    __shared__ float xl[NN][36];         // 18.4 KB  (rows 144B, 16B aligned)
    __shared__ float hlT[ATOM][132];     // 17.9 KB  h transposed
    __shared__ float att[32][NN];        // 16 KB
    __shared__ float wg[ATOM * ATOM];
    __shared__ float fs[NN], fd[NN];
    __shared__ float bgs[ATOM], avs[2 * ATOM];

    for (int i = t; i < ATOM * ATOM; i += 512) wg[i] = Wg[i];
    if (t < ATOM)     bgs[t] = bg[t];
    if (t < 2 * ATOM) avs[t] = av[t];
    const float* xp = xsrc + b * NA;
    for (int i = t; i < NA; i += 512) xl[i / ATOM][i % ATOM] = xp[i];
    __syncthreads();

    // h^T = relu(x @ Wg + bg)^T : thread (n, sub) does 8-9 e's, x-row in regs,
    // wg reads are 4-address broadcasts.
    {
        const int n = t >> 2, sub = t & 3;
        float xr[36];
        float4* xr4 = (float4*)xr;
        const float4* xlr = (const float4*)&xl[n][0];
        #pragma unroll
        for (int k = 0; k < 9; ++k) xr4[k] = xlr[k];
        for (int e = sub; e < ATOM; e += 4) {
            float acc = bgs[e];
            #pragma unroll
            for (int d = 0; d < ATOM; ++d) acc += xr[d] * wg[d * ATOM + e];
            hlT[e][n] = fmaxf(acc, 0.f);
        }
    }
    __syncthreads();

    // fs/fd
    if (t < 2 * NN) {
        const int n = t & (NN - 1), w = t >> 7;
        const float* avp = avs + w * ATOM;
        float acc = 0.f;
        #pragma unroll
        for (int d = 0; d < ATOM; ++d) acc += hlT[d][n] * avp[d];
        if (w == 0) fs[n] = acc; else fd[n] = acc;
    }
    __syncthreads();

    // masked softmax for this block's 32 rows (8 waves x 4 rows)
    const int* Ab = A + b * NN * NN;
    #pragma unroll
    for (int i = 0; i < 4; ++i) {
        int lp = wave * 4 + i, gp = p0 + lp;
        float fsv = fs[gp];
        unsigned long long m0 = __ballot(Ab[gp * NN + lane] > 0);
        unsigned long long m1 = __ballot(Ab[gp * NN + 64 + lane] > 0);
        float s0 = fsv + fd[lane];
        s0 = (s0 > 0.f) ? s0 : 0.01f * s0;
        if (!((m0 >> lane) & 1ull)) s0 = NEGF;
        float s1 = fsv + fd[64 + lane];
        s1 = (s1 > 0.f) ? s1 : 0.01f * s1;
        if (!((m1 >> lane) & 1ull)) s1 = NEGF;
        float mx = fmaxf(s0, s1);
        #pragma unroll
        for (int o = 32; o >= 1; o >>= 1) mx = fmaxf(mx, __shfl_xor(mx, o, 64));
        float e0 = __expf(s0 - mx), e1 = __expf(s1 - mx);
        float sm = e0 + e1;
        #pragma unroll
        for (int o = 32; o >= 1; o >>= 1) sm += __shfl_xor(sm, o, 64);
        float inv = 1.f / sm;
        att[lp][lane]      = e0 * inv;
        att[lp][64 + lane] = e1 * inv;
    }
    __syncthreads();

    // x_out = x + att @ h : thread (p, g) owns d = {g, g+16} (+32/33 for g<2);
    // both operands read as float4.
    {
        const int p = t >> 4, g = t & 15;
        const float4* ap  = (const float4*)&att[p][0];
        const float4* h1p = (const float4*)&hlT[g][0];
        const float4* h2p = (const float4*)&hlT[g + 16][0];
        float a1 = 0.f, a2 = 0.f;
        #pragma unroll 8
        for (int k = 0; k < 32; ++k) {
            float4 a4 = ap[k], x1 = h1p[k], x2 = h2p[k];
            a1 += a4.x * x1.x + a4.y * x1.y + a4.z * x1.z + a4.w * x1.w;
            a2 += a4.x * x2.x + a4.y * x2.y + a4.z * x2.z + a4.w * x2.w;
        }
        const int gp = p0 + p;
        float* Xr = X + b * NA + gp * ATOM;
        Xr[g]      = xl[gp][g] + a1;
        Xr[g + 16] = xl[gp][g + 16] + a2;
        if (g < 2) {
            const float4* h3p = (const float4*)&hlT[g + 32][0];
            float a3 = 0.f;
            #pragma unroll 8
            for (int k = 0; k < 32; ++k) {
                float4 a4 = ap[k], x3 = h3p[k];
                a3 += a4.x * x3.x + a4.y * x3.y + a4.z * x3.z + a4.w * x3.w;
            }
            Xr[g + 32] = xl[gp][g + 32] + a3;
        }
    }
}

// ---------------- K2: phaseB ----------------
// grid 256, block 512 = 32 rows x 16 h-subgroups; float4 LDS reads throughout.
__global__ __launch_bounds__(512) void k_phaseB(
    const float* __restrict__ X, const float* __restrict__ xs,
    const float* __restrict__ Wt, const float* __restrict__ bt,
    const float* __restrict__ Wf, const float* __restrict__ bf,
    const float* __restrict__ Wf2, const float* __restrict__ bf2,
    float* __restrict__ DM)
{
    const int b = blockIdx.x >> 2, q4 = blockIdx.x & 3;
    const int t = threadIdx.x;
    const int p0 = q4 * 32;
    __shared__ float wt[HID * 36];       // [h][d] transposed; 36.9 KB (reused: partials 0..7)
    __shared__ float wf[HID * 36];       // [h][j];            36.9 KB (reused: partials 8..15)
    __shared__ float xl[32][36];
    __shared__ float dlT[ATOM][33];      // d transposed for Wf2 phase
    __shared__ float wf2s[ATOM * LATENT];
    __shared__ float bts[HID];
    __shared__ float bfs[ATOM];
    __shared__ float sl[512];

    for (int i = t; i < ATOM * HID; i += 512) {
        int d = i >> 8, h = i & 255;               // Wt is [d][h]
        wt[h * 36 + d] = Wt[i];
    }
    for (int i = t; i < HID * ATOM; i += 512) {
        int h = i / ATOM, j = i % ATOM;            // Wf is [h][j]
        wf[h * 36 + j] = Wf[i];
    }
    for (int i = t; i < ATOM * LATENT; i += 512) wf2s[i] = Wf2[i];
    if (t < HID)  bts[t] = bt[t];
    if (t < ATOM) bfs[t] = bf[t];
    for (int i = t; i < 32 * ATOM; i += 512) xl[i / ATOM][i % ATOM] = X[b * NA + p0 * ATOM + i];
    __syncthreads();

    const int row = t & 31, sub = t >> 5;          // sub 0..15
    float dp[ATOM];
    #pragma unroll
    for (int j = 0; j < ATOM; ++j) dp[j] = 0.f;
    {
        float xr[36];
        float4* xr4 = (float4*)xr;
        const float4* xlr = (const float4*)&xl[row][0];
        #pragma unroll
        for (int k = 0; k < 9; ++k) xr4[k] = xlr[k];
        for (int i = 0; i < 16; ++i) {
            const int h = sub + 16 * i;
            float acc = bts[h];
            const float4* wtp = (const float4*)&wt[h * 36];
            #pragma unroll
            for (int k = 0; k < 8; ++k) {
                float4 w4 = wtp[k];
                acc += xr[4*k] * w4.x + xr[4*k+1] * w4.y + xr[4*k+2] * w4.z + xr[4*k+3] * w4.w;
            }
            acc += xr[32] * wt[h * 36 + 32] + xr[33] * wt[h * 36 + 33];
            acc = fmaxf(acc, 0.f);
            const float4* wfp = (const float4*)&wf[h * 36];
            #pragma unroll
            for (int k = 0; k < 8; ++k) {
                float4 w4 = wfp[k];
                dp[4*k]   += acc * w4.x; dp[4*k+1] += acc * w4.y;
                dp[4*k+2] += acc * w4.z; dp[4*k+3] += acc * w4.w;
            }
            dp[32] += acc * wf[h * 36 + 32];
            dp[33] += acc * wf[h * 36 + 33];
        }
    }
    __syncthreads();                               // done with wt/wf weights
    {
        float* pl = (sub < 8) ? wt : wf;
        const int s8 = sub & 7;
        #pragma unroll
        for (int j = 0; j < ATOM; ++j) pl[(s8 * 32 + row) * ATOM + j] = dp[j];
    }
    __syncthreads();
    for (int i = t; i < 32 * ATOM; i += 512) {
        int rr = i / ATOM, j = i % ATOM;
        float dv = bfs[j] + xs[b * NA + (p0 + rr) * ATOM + j];
        #pragma unroll
        for (int s = 0; s < 8; ++s)
            dv += wt[(s * 32 + rr) * ATOM + j] + wf[(s * 32 + rr) * ATOM + j];
        dlT[j][rr] = dv;
    }
    __syncthreads();
    // d @ Wf2 + bf2 with Wf2 column register-cached; partial max over 8 rows
    {
        const int l = t & 127, chunk = t >> 7;
        float w2r[ATOM];
        #pragma unroll
        for (int j = 0; j < ATOM; ++j) w2r[j] = wf2s[j * LATENT + l];
        float mx = -3.4e38f;
        for (int rr = chunk * 8; rr < chunk * 8 + 8; ++rr) {
            float acc = bf2[l];
            #pragma unroll
            for (int j = 0; j < ATOM; ++j) acc += dlT[j][rr] * w2r[j];
            mx = fmaxf(mx, acc);
        }
        sl[chunk * 128 + l] = mx;
    }
    __syncthreads();
    if (t < LATENT)
        DM[(b * 4 + q4) * LATENT + t] =
            fmaxf(fmaxf(sl[t], sl[128 + t]), fmaxf(sl[256 + t], sl[384 + t]));
}

// ---------------- K3: full decoder, k-split partial sums ----------------
// grid 64, block 1024 (16 waves)
__global__ __launch_bounds__(1024) void k_dec(
    const float* __restrict__ DM, const float* __restrict__ cell,
    const float* __restrict__ W1, const float* __restrict__ b1,
    const float* __restrict__ W2, const float* __restrict__ b2,
    const float* __restrict__ W3, const float* __restrict__ b3,
    const float* __restrict__ W4, const float* __restrict__ b4,
    float* __restrict__ out)
{
    const int b = blockIdx.x, t = threadIdx.x, lane = t & 63, wave = t >> 6;
    __shared__ float vec[LATENT + CELLS];
    __shared__ float h1[128], h2[256], h3[512];
    __shared__ float sl[1024];
    if (t < LATENT) {
        float m = fmaxf(fmaxf(DM[(b*4+0)*LATENT + t], DM[(b*4+1)*LATENT + t]),
                        fmaxf(DM[(b*4+2)*LATENT + t], DM[(b*4+3)*LATENT + t]));
        vec[t] = 1.f / (1.f + __expf(-m));
    } else if (t >= 512) {
        int c = t - 512;
        vec[LATENT + c] = 1.f / (1.f + __expf(-cell[b * CELLS + c]));
    }
    __syncthreads();
    // L1: 640->128, 8-way k-split (80 each)
    {
        const int j = t & 127, part = t >> 7;
        float acc = 0.f;
        #pragma unroll 4
        for (int k = part * 80; k < part * 80 + 80; ++k)
            acc += vec[k] * W1[k * 128 + j];
        sl[part * 128 + j] = acc;
    }
    __syncthreads();
    if (t < 128) {
        float v = b1[t];
        #pragma unroll
        for (int p = 0; p < 8; ++p) v += sl[p * 128 + t];
        h1[t] = fmaxf(v, 0.f);
    }
    __syncthreads();
    // L2: 128->256, 4-way k-split (32 each)
    {
        const int j = t & 255, part = t >> 8;
        float acc = 0.f;
        #pragma unroll 4
        for (int k = part * 32; k < part * 32 + 32; ++k)
            acc += h1[k] * W2[k * 256 + j];
        sl[part * 256 + j] = acc;
    }
    __syncthreads();
    if (t < 256) h2[t] = fmaxf(sl[t] + sl[256 + t] + sl[512 + t] + sl[768 + t] + b2[t], 0.f);
    __syncthreads();
    // L3: 256->512, 2-way k-split (128 each)
    {
        const int j = t & 511, part = t >> 9;
        float acc = 0.f;
        #pragma unroll 4
        for (int k = part * 128; k < part * 128 + 128; ++k)
            acc += h2[k] * W3[k * 512 + j];
        sl[part * 512 + j] = acc;
    }
    __syncthreads();
    if (t < 512) h3[t] = fmaxf(sl[t] + sl[512 + t] + b3[t], 0.f);
    __syncthreads();
    float v = (t < 512) ? h3[t] * W4[t] : 0.f;
    #pragma unroll
    for (int o = 32; o >= 1; o >>= 1) v += __shfl_xor(v, o, 64);
    if (lane == 0) sl[wave] = v;
    __syncthreads();
    if (t == 0) {
        float s = b4[0];
        #pragma unroll
        for (int w = 0; w < 16; ++w) s += sl[w];
        out[b] = s;
    }
}

extern "C" void kernel_launch(void* const* d_in, const int* in_sizes, int n_in,
                              void* d_out, int out_size, void* d_ws, size_t ws_size,
                              hipStream_t stream) {
    const float* xs       = (const float*)d_in[0];
    const int*   A        = (const int*)  d_in[1];
    const float* cell_emb = (const float*)d_in[2];
    const float* Wg       = (const float*)d_in[3];
    const float* bg       = (const float*)d_in[4];
    const float* attnv    = (const float*)d_in[5];
    const float* Wt       = (const float*)d_in[6];
    const float* bt       = (const float*)d_in[7];
    const float* Wf       = (const float*)d_in[8];
    const float* bf       = (const float*)d_in[9];
    const float* Wf2      = (const float*)d_in[10];
    const float* bf2      = (const float*)d_in[11];
    const float* W1       = (const float*)d_in[12];
    const float* b1       = (const float*)d_in[13];
    const float* W2       = (const float*)d_in[14];
    const float* b2       = (const float*)d_in[15];
    const float* W3       = (const float*)d_in[16];
    const float* b3       = (const float*)d_in[17];
    const float* W4       = (const float*)d_in[18];
    const float* b4       = (const float*)d_in[19];
    float* out = (float*)d_out;

    float* W  = (float*)d_ws;
    float* X0 = W;                 // 64*4352
    float* X1 = W + 278528;        // 64*4352  (ping-pong: fixes cross-block in-place race)
    float* DM = W + 557056;        // 64*4*128

    k_gat<<<256, 512, 0, stream>>>(xs, A, Wg,                  bg,          attnv,          X0);
    k_gat<<<256, 512, 0, stream>>>(X0, A, Wg + ATOM * ATOM,    bg + ATOM,   attnv + 2*ATOM, X1);
    k_gat<<<256, 512, 0, stream>>>(X1, A, Wg + 2 * ATOM * ATOM, bg + 2*ATOM, attnv + 4*ATOM, X0);
    k_phaseB<<<256, 512, 0, stream>>>(X0, xs, Wt, bt, Wf, bf, Wf2, bf2, DM);
    k_dec<<<64, 1024, 0, stream>>>(DM, cell_emb, W1, b1, W2, b2, W3, b3, W4, b4, out);
}